// Round 1
// baseline (1993.176 us; speedup 1.0000x reference)
//
#include <hip/hip_runtime.h>
#include <hip/hip_bf16.h>
#include <stdint.h>

typedef __bf16 bf16;
typedef __bf16 bf16x4_t __attribute__((ext_vector_type(4)));
typedef __bf16 bf16x8_t __attribute__((ext_vector_type(8)));
typedef float floatx4_t __attribute__((ext_vector_type(4)));

#define IN_CH 1280
#define G_CH 128
#define HID 512
#define NCLS 79

// ---------------- small utility kernels ----------------

// W: [K][O] row-major fp32  ->  WT: [Opad][K] bf16 (rows >= O zero-filled)
__global__ void k_transpose_w(const float* __restrict__ W, bf16* __restrict__ WT,
                              int K, int O, int Opad) {
  int idx = blockIdx.x * 256 + threadIdx.x;
  int total = Opad * K;
  if (idx >= total) return;
  int o = idx / K, k = idx - o * K;
  float v = (o < O) ? W[(size_t)k * O + o] : 0.f;
  WT[(size_t)o * K + k] = (bf16)v;
}

__global__ void k_zero2(int* __restrict__ a, int* __restrict__ b, int n) {
  int i = blockIdx.x * 256 + threadIdx.x;
  if (i < n) { a[i] = 0; b[i] = 0; }
}

__global__ void k_count(const int* __restrict__ col, int* __restrict__ cnt, int E) {
  int e = blockIdx.x * 256 + threadIdx.x;
  if (e < E) atomicAdd(&cnt[col[e]], 1);
}

__global__ void k_dinv(const int* __restrict__ cnt, float* __restrict__ dinv, int n) {
  int i = blockIdx.x * 256 + threadIdx.x;
  if (i < n) dinv[i] = rsqrtf((float)cnt[i] + 1.0f);  // +1 self-loop
}

// exclusive prefix sum over n counts; single block of 1024 threads
__global__ __launch_bounds__(1024) void k_scan(const int* __restrict__ cnt,
                                               int* __restrict__ offs, int n) {
  __shared__ int sums[1024];
  int t = threadIdx.x;
  int ch = (n + 1023) >> 10;
  int beg = t * ch;
  int end = beg + ch; if (end > n) end = n; if (beg > n) beg = n;
  int s = 0;
  for (int i = beg; i < end; ++i) s += cnt[i];
  sums[t] = s;
  __syncthreads();
  for (int off = 1; off < 1024; off <<= 1) {
    int add = (t >= off) ? sums[t - off] : 0;
    int v = sums[t];
    __syncthreads();
    sums[t] = v + add;
    __syncthreads();
  }
  int run = (t == 0) ? 0 : sums[t - 1];
  for (int i = beg; i < end; ++i) { offs[i] = run; run += cnt[i]; }
}

__global__ void k_scatter(const int* __restrict__ srcs, const int* __restrict__ dsts,
                          const int* __restrict__ offs, int* __restrict__ cursor,
                          int* __restrict__ csr, int E) {
  int e = blockIdx.x * 256 + threadIdx.x;
  if (e < E) {
    int t = dsts[e];
    int p = offs[t] + atomicAdd(&cursor[t], 1);
    csr[p] = srcs[e];
  }
}

// one wave per node: x1 = relu((sum_{s->t} dinv[s]*xw[s] + dinv[t]*xw[t]) * dinv[t] + b)
__global__ __launch_bounds__(64) void k_aggregate(
    const float* __restrict__ xw, const float* __restrict__ dinv,
    const int* __restrict__ offs, const int* __restrict__ cnt,
    const int* __restrict__ csr, const float* __restrict__ b_gcn,
    bf16* __restrict__ x1, int n) {
  int node = blockIdx.x;
  if (node >= n) return;
  int lane = threadIdx.x;  // 64 lanes * float2 = 128 channels
  float di = dinv[node];
  const float2* self = (const float2*)(xw + (size_t)node * G_CH);
  float2 v = self[lane];
  float ax = v.x * di, ay = v.y * di;
  int beg = offs[node], c = cnt[node];
  for (int i = 0; i < c; ++i) {
    int s = csr[beg + i];
    float ds = dinv[s];
    const float2* r = (const float2*)(xw + (size_t)s * G_CH);
    float2 u = r[lane];
    ax += u.x * ds; ay += u.y * ds;
  }
  float ox = fmaxf(ax * di + b_gcn[2 * lane], 0.f);
  float oy = fmaxf(ay * di + b_gcn[2 * lane + 1], 0.f);
  x1[(size_t)node * G_CH + 2 * lane] = (bf16)ox;
  x1[(size_t)node * G_CH + 2 * lane + 1] = (bf16)oy;
}

// ---------------- bf16 MFMA GEMM ----------------
// C[M x N] = A[M x K] * B[K x N] (B passed transposed: BT[N][K] bf16)
// A source 1: fp32 (cols [0,K1)); A source 2 (optional): bf16 (cols [K1,K))
// Wave tile = (BM/WAVES_M) x (BN/WAVES_N), 16x16x32 bf16 MFMA fragments.
template<int BM, int BN, int BK, int WAVES_M, int WAVES_N, bool RELU, bool BIAS, int NCLIP>
__global__ __launch_bounds__(256) void k_gemm(
    const float* __restrict__ A1, int lda1, int K1,
    const bf16* __restrict__ A2, int lda2,
    const bf16* __restrict__ BT, int K,
    const float* __restrict__ bias,
    float* __restrict__ C, int ldc, int M) {
  constexpr int LDA = BK + 8;        // pad 8 bf16 = 16B: breaks row-stride bank aliasing
  constexpr int WMr = BM / WAVES_M;
  constexpr int WNc = BN / WAVES_N;
  constexpr int MT = WMr / 16;
  constexpr int NT = WNc / 16;
  __shared__ __align__(16) bf16 Al[BM][LDA];
  __shared__ __align__(16) bf16 Bl[BN][LDA];

  int tid = threadIdx.x;
  int lane = tid & 63;
  int w = tid >> 6;
  int waveM = w / WAVES_N;
  int waveN = w % WAVES_N;
  int row0 = blockIdx.x * BM;
  int col0 = blockIdx.y * BN;

  int aRow = waveM * WMr + (lane & 15);   // A frag: m = lane&15
  int bRow = waveN * WNc + (lane & 15);   // B frag: n = lane&15 (rows of BT)
  int kLane = (lane >> 4) * 8;            // k = quad*8 + j

  floatx4_t acc[MT][NT];
#pragma unroll
  for (int i = 0; i < MT; ++i)
#pragma unroll
    for (int j = 0; j < NT; ++j)
      acc[i][j] = (floatx4_t){0.f, 0.f, 0.f, 0.f};

  for (int k0 = 0; k0 < K; k0 += BK) {
    // ---- stage A tile (convert fp32->bf16, or copy bf16) ----
    if (A2 == nullptr || k0 < K1) {
#pragma unroll
      for (int c = 0; c < (BM * BK / 4) / 256; ++c) {
        int ci = c * 256 + tid;
        int r = ci / (BK / 4);
        int c4 = ci % (BK / 4);
        int gr = row0 + r;
        float4 v = {0.f, 0.f, 0.f, 0.f};
        if (gr < M) v = *(const float4*)(A1 + (size_t)gr * lda1 + k0 + c4 * 4);
        bf16x4_t pkt = {(bf16)v.x, (bf16)v.y, (bf16)v.z, (bf16)v.w};
        *(bf16x4_t*)&Al[r][c4 * 4] = pkt;
      }
    } else {
#pragma unroll
      for (int c = 0; c < (BM * BK / 8) / 256; ++c) {
        int ci = c * 256 + tid;
        int r = ci / (BK / 8);
        int c8 = ci % (BK / 8);
        int gr = row0 + r;
        bf16x8_t v = {(bf16)0.f,(bf16)0.f,(bf16)0.f,(bf16)0.f,
                      (bf16)0.f,(bf16)0.f,(bf16)0.f,(bf16)0.f};
        if (gr < M) v = *(const bf16x8_t*)(A2 + (size_t)gr * lda2 + (k0 - K1) + c8 * 8);
        *(bf16x8_t*)&Al[r][c8 * 8] = v;
      }
    }
    // ---- stage B tile (already bf16, rows of BT are contiguous in k) ----
    for (int ci = tid; ci < BN * (BK / 8); ci += 256) {
      int nrow = ci / (BK / 8);
      int c8 = ci % (BK / 8);
      bf16x8_t v = *(const bf16x8_t*)(BT + (size_t)(col0 + nrow) * K + k0 + c8 * 8);
      *(bf16x8_t*)&Bl[nrow][c8 * 8] = v;
    }
    __syncthreads();

#pragma unroll
    for (int kk = 0; kk < BK; kk += 32) {
      bf16x8_t af[MT], bfr[NT];
#pragma unroll
      for (int mt = 0; mt < MT; ++mt)
        af[mt] = *(const bf16x8_t*)&Al[aRow + mt * 16][kk + kLane];
#pragma unroll
      for (int nt = 0; nt < NT; ++nt)
        bfr[nt] = *(const bf16x8_t*)&Bl[bRow + nt * 16][kk + kLane];
#pragma unroll
      for (int mt = 0; mt < MT; ++mt)
#pragma unroll
        for (int nt = 0; nt < NT; ++nt)
          acc[mt][nt] = __builtin_amdgcn_mfma_f32_16x16x32_bf16(
              af[mt], bfr[nt], acc[mt][nt], 0, 0, 0);
    }
    __syncthreads();
  }

  // ---- epilogue: C/D layout col=lane&15, row=(lane>>4)*4+reg ----
#pragma unroll
  for (int mt = 0; mt < MT; ++mt) {
    int gr0 = row0 + waveM * WMr + mt * 16 + (lane >> 4) * 4;
#pragma unroll
    for (int r = 0; r < 4; ++r) {
      int gr = gr0 + r;
      if (gr >= M) continue;
#pragma unroll
      for (int nt = 0; nt < NT; ++nt) {
        int gc = col0 + waveN * WNc + nt * 16 + (lane & 15);
        if (NCLIP > 0 && gc >= NCLIP) continue;
        float v = acc[mt][nt][r];
        if (BIAS) v += bias[gc];
        if (RELU) v = fmaxf(v, 0.f);
        C[(size_t)gr * ldc + gc] = v;
      }
    }
  }
}

// ---------------- launcher ----------------
extern "C" void kernel_launch(void* const* d_in, const int* in_sizes, int n_in,
                              void* d_out, int out_size, void* d_ws, size_t ws_size,
                              hipStream_t stream) {
  (void)n_in; (void)out_size; (void)ws_size;
  const float* x  = (const float*)d_in[0];
  const int*   ei = (const int*)d_in[1];
  // d_in[2] = img_sizes, unused by the reference
  const float* Wg = (const float*)d_in[3];
  const float* bg = (const float*)d_in[4];
  const float* Wh = (const float*)d_in[5];
  const float* bh = (const float*)d_in[6];
  const float* Wc = (const float*)d_in[7];
  const float* bc = (const float*)d_in[8];
  float* out = (float*)d_out;

  int Nn = in_sizes[0] / IN_CH;   // 100000
  int E  = in_sizes[1] / 2;       // 625000
  const int* e_src = ei;          // edge_index[0] = sources
  const int* e_dst = ei + E;      // edge_index[1] = targets

  // workspace carve (~83 MB total)
  char* p = (char*)d_ws;
  auto carve = [&](size_t bytes) -> char* {
    char* q = p; p += (bytes + 255) & ~(size_t)255; return q;
  };
  bf16*  wgT    = (bf16*)carve((size_t)G_CH * IN_CH * 2);
  bf16*  whT    = (bf16*)carve((size_t)HID * (IN_CH + G_CH) * 2);
  bf16*  wcT    = (bf16*)carve((size_t)80 * HID * 2);
  float* xw     = (float*)carve((size_t)Nn * G_CH * 4);
  bf16*  x1     = (bf16*)carve((size_t)Nn * G_CH * 2);
  int*   cnt    = (int*)carve((size_t)Nn * 4);
  int*   cursor = (int*)carve((size_t)Nn * 4);
  int*   offs   = (int*)carve((size_t)Nn * 4);
  float* dinv   = (float*)carve((size_t)Nn * 4);
  int*   csr    = (int*)carve((size_t)E * 4);

  int gN = (Nn + 255) / 256;
  int gE = (E + 255) / 256;
  int gM = (Nn + 127) / 128;

  // weights -> transposed bf16
  k_transpose_w<<<(G_CH * IN_CH + 255) / 256, 256, 0, stream>>>(Wg, wgT, IN_CH, G_CH, G_CH);
  k_transpose_w<<<(HID * (IN_CH + G_CH) + 255) / 256, 256, 0, stream>>>(Wh, whT, IN_CH + G_CH, HID, HID);
  k_transpose_w<<<(80 * HID + 255) / 256, 256, 0, stream>>>(Wc, wcT, HID, NCLS, 80);

  // degree + CSR build
  k_zero2<<<gN, 256, 0, stream>>>(cnt, cursor, Nn);
  k_count<<<gE, 256, 0, stream>>>(e_dst, cnt, E);
  k_dinv<<<gN, 256, 0, stream>>>(cnt, dinv, Nn);
  k_scan<<<1, 1024, 0, stream>>>(cnt, offs, Nn);
  k_scatter<<<gE, 256, 0, stream>>>(e_src, e_dst, offs, cursor, csr, E);

  // GEMM1: xw = x @ W_gcn   [N,1280]x[1280,128]
  k_gemm<128, 128, 64, 2, 2, false, false, 0><<<dim3(gM, 1), 256, 0, stream>>>(
      x, IN_CH, IN_CH, nullptr, 0, wgT, IN_CH, nullptr, xw, G_CH, Nn);

  // aggregation -> x1 (bf16, with relu + bias)
  k_aggregate<<<Nn, 64, 0, stream>>>(xw, dinv, offs, cnt, csr, bg, x1, Nn);

  // GEMM2: h = relu([x | x1] @ W_hid + b_hid) -> d_out[0 : N*512]
  k_gemm<128, 128, 64, 2, 2, true, true, 0><<<dim3(gM, 4), 256, 0, stream>>>(
      x, IN_CH, IN_CH, x1, G_CH, whT, IN_CH + G_CH, bh, out, HID, Nn);

  // GEMM3: logits = h @ W_cls + b_cls -> d_out[N*512 : N*512 + N*79]
  k_gemm<128, 80, 64, 4, 1, false, true, NCLS><<<dim3(gM, 1), 256, 0, stream>>>(
      out, HID, HID, nullptr, 0, wcT, HID, bc, out + (size_t)Nn * HID, NCLS, Nn);
}

// Round 2
// 1402.402 us; speedup vs baseline: 1.4213x; 1.4213x over previous
//
#include <hip/hip_runtime.h>
#include <hip/hip_bf16.h>
#include <stdint.h>

typedef __bf16 bf16;
typedef __bf16 bf16x2_t __attribute__((ext_vector_type(2)));
typedef __bf16 bf16x4_t __attribute__((ext_vector_type(4)));
typedef __bf16 bf16x8_t __attribute__((ext_vector_type(8)));
typedef float floatx4_t __attribute__((ext_vector_type(4)));

#define IN_CH 1280
#define G_CH 128
#define KCAT 1408   // IN_CH + G_CH
#define HID 512
#define NCLS 79

// async 16B global->LDS (lds dest = wave-uniform base + lane*16)
#define ASYNC_CP16(g, l)                                              \
  __builtin_amdgcn_global_load_lds(                                   \
      (const __attribute__((address_space(1))) void*)(g),             \
      (__attribute__((address_space(3))) void*)(l), 16, 0, 0)

// ---------------- small utility kernels ----------------

// W: [K][O] row-major fp32  ->  WT: [Opad][K] bf16 (rows >= O zero-filled)
__global__ void k_transpose_w(const float* __restrict__ W, bf16* __restrict__ WT,
                              int K, int O, int Opad) {
  int idx = blockIdx.x * 256 + threadIdx.x;
  int total = Opad * K;
  if (idx >= total) return;
  int o = idx / K, k = idx - o * K;
  float v = (o < O) ? W[(size_t)k * O + o] : 0.f;
  WT[(size_t)o * K + k] = (bf16)v;
}

// x fp32 [N][1280] -> xcat bf16 [Npad][1408] cols 0..1279
__global__ void k_convert(const float* __restrict__ x, bf16* __restrict__ xcat, int n8) {
  int i = blockIdx.x * 256 + threadIdx.x;
  if (i >= n8) return;
  int row = i / 160, j = (i - row * 160) * 8;
  const float4* p = (const float4*)(x + (size_t)row * IN_CH + j);
  float4 a = p[0], b = p[1];
  bf16x8_t o = {(bf16)a.x, (bf16)a.y, (bf16)a.z, (bf16)a.w,
                (bf16)b.x, (bf16)b.y, (bf16)b.z, (bf16)b.w};
  *(bf16x8_t*)(xcat + (size_t)row * KCAT + j) = o;
}

__global__ void k_zero2(int* __restrict__ a, int* __restrict__ b, int n) {
  int i = blockIdx.x * 256 + threadIdx.x;
  if (i < n) { a[i] = 0; b[i] = 0; }
}

__global__ void k_count(const int* __restrict__ col, int* __restrict__ cnt, int E) {
  int e = blockIdx.x * 256 + threadIdx.x;
  if (e < E) atomicAdd(&cnt[col[e]], 1);
}

__global__ void k_dinv(const int* __restrict__ cnt, float* __restrict__ dinv, int n) {
  int i = blockIdx.x * 256 + threadIdx.x;
  if (i < n) dinv[i] = rsqrtf((float)cnt[i] + 1.0f);  // +1 self-loop
}

// exclusive prefix sum over n counts; single block of 1024 threads
__global__ __launch_bounds__(1024) void k_scan(const int* __restrict__ cnt,
                                               int* __restrict__ offs, int n) {
  __shared__ int sums[1024];
  int t = threadIdx.x;
  int ch = (n + 1023) >> 10;
  int beg = t * ch;
  int end = beg + ch; if (end > n) end = n; if (beg > n) beg = n;
  int s = 0;
  for (int i = beg; i < end; ++i) s += cnt[i];
  sums[t] = s;
  __syncthreads();
  for (int off = 1; off < 1024; off <<= 1) {
    int add = (t >= off) ? sums[t - off] : 0;
    int v = sums[t];
    __syncthreads();
    sums[t] = v + add;
    __syncthreads();
  }
  int run = (t == 0) ? 0 : sums[t - 1];
  for (int i = beg; i < end; ++i) { offs[i] = run; run += cnt[i]; }
}

__global__ void k_scatter(const int* __restrict__ srcs, const int* __restrict__ dsts,
                          const int* __restrict__ offs, int* __restrict__ cursor,
                          int* __restrict__ csr, int E) {
  int e = blockIdx.x * 256 + threadIdx.x;
  if (e < E) {
    int t = dsts[e];
    int p = offs[t] + atomicAdd(&cursor[t], 1);
    csr[p] = srcs[e];
  }
}

// xw bf16 rows already scaled by dinv[row]; out = relu((sum neigh + self)*dinv[t] + b)
// 4 waves/block, one node per wave, lane covers 2 channels
__global__ __launch_bounds__(256) void k_aggregate2(
    const bf16* __restrict__ xw, const float* __restrict__ dinv,
    const int* __restrict__ offs, const int* __restrict__ cnt,
    const int* __restrict__ csr, const float* __restrict__ bg,
    bf16* __restrict__ xcat, int n) {
  int node = blockIdx.x * 4 + (threadIdx.x >> 6);
  if (node >= n) return;
  int lane = threadIdx.x & 63;
  bf16x2_t v = ((const bf16x2_t*)(xw + (size_t)node * G_CH))[lane];
  float ax = (float)v.x, ay = (float)v.y;
  int beg = offs[node], c = cnt[node];
  for (int i = 0; i < c; ++i) {
    int s = csr[beg + i];
    bf16x2_t u = ((const bf16x2_t*)(xw + (size_t)s * G_CH))[lane];
    ax += (float)u.x; ay += (float)u.y;
  }
  float dv = dinv[node];
  float2 b = ((const float2*)bg)[lane];
  bf16x2_t o;
  o.x = (bf16)fmaxf(ax * dv + b.x, 0.f);
  o.y = (bf16)fmaxf(ay * dv + b.y, 0.f);
  ((bf16x2_t*)(xcat + (size_t)node * KCAT + IN_CH))[lane] = o;
}

// ---------------- async bf16 MFMA GEMM (m97-style + XOR swizzle) ----------------
// C[M x N] = A[M x K] * BT[N][K]^T. BK=64 (128 B rows), tiles unpadded.
// LDS chunk layout: 16B chunk c of row r stored at position (c ^ (r&7)) in row r.
// Staged by global_load_lds: lane L of seg s loads row s*8+L/8, global chunk
// ((L&7) ^ (row&7)) -> LDS lands at the swizzled slot automatically.
template<int BM, int BN, int WM, int WN, bool RELU, bool BIAS, bool DINV,
         bool SF32, bool SBF16, int NCLIP>
__global__ __launch_bounds__(256) void k_gemm_async(
    const bf16* __restrict__ A, int lda,
    const bf16* __restrict__ BT, int ldb, int K,
    const float* __restrict__ bias, const float* __restrict__ dinv,
    float* __restrict__ Cf, bf16* __restrict__ Cb, int ldc, int M) {
  constexpr int BK = 64;
  constexpr int WMr = BM / WM, WNc = BN / WN;
  constexpr int MT = WMr / 16, NT = WNc / 16;
  __shared__ __align__(16) bf16 Al[BM * BK];
  __shared__ __align__(16) bf16 Bl[BN * BK];

  int tid = threadIdx.x, lane = tid & 63, w = tid >> 6;
  int waveM = w / WN, waveN = w % WN;
  int col0 = blockIdx.x * BN, row0 = blockIdx.y * BM;
  int q = lane >> 4, m16 = lane & 15;
  int srow = lane >> 3, scol = lane & 7;   // staging: row-in-seg, chunk id

  floatx4_t acc[MT][NT];
#pragma unroll
  for (int i = 0; i < MT; ++i)
#pragma unroll
    for (int j = 0; j < NT; ++j)
      acc[i][j] = (floatx4_t){0.f, 0.f, 0.f, 0.f};

  for (int k0 = 0; k0 < K; k0 += BK) {
    // A tile: BM/8 segs of 1024 B
#pragma unroll
    for (int i = 0; i < BM / 32; ++i) {
      int s = i * 4 + w;
      int m = s * 8 + srow;
      int c = scol ^ (m & 7);
      ASYNC_CP16(A + (size_t)(row0 + m) * lda + k0 + c * 8, Al + s * 512);
    }
    // B tile: BN/8 segs
    for (int s = w; s < BN / 8; s += 4) {
      int nr = s * 8 + srow;
      int c = scol ^ (nr & 7);
      ASYNC_CP16(BT + (size_t)(col0 + nr) * ldb + k0 + c * 8, Bl + s * 512);
    }
    __syncthreads();

#pragma unroll
    for (int kk = 0; kk < 2; ++kk) {
      bf16x8_t af[MT], bfr[NT];
#pragma unroll
      for (int mt = 0; mt < MT; ++mt) {
        int m = waveM * WMr + mt * 16 + m16;
        int p = (kk * 4 + q) ^ (m & 7);
        af[mt] = *(const bf16x8_t*)(Al + m * 64 + p * 8);
      }
#pragma unroll
      for (int nt = 0; nt < NT; ++nt) {
        int nn = waveN * WNc + nt * 16 + m16;
        int p = (kk * 4 + q) ^ (nn & 7);
        bfr[nt] = *(const bf16x8_t*)(Bl + nn * 64 + p * 8);
      }
#pragma unroll
      for (int mt = 0; mt < MT; ++mt)
#pragma unroll
        for (int nt = 0; nt < NT; ++nt)
          acc[mt][nt] = __builtin_amdgcn_mfma_f32_16x16x32_bf16(
              af[mt], bfr[nt], acc[mt][nt], 0, 0, 0);
    }
    __syncthreads();
  }

  // epilogue: C/D layout col=lane&15, row=quad*4+reg
#pragma unroll
  for (int mt = 0; mt < MT; ++mt) {
    int gr0 = row0 + waveM * WMr + mt * 16 + q * 4;
#pragma unroll
    for (int r = 0; r < 4; ++r) {
      int gr = gr0 + r;
      if (gr >= M) continue;
      float dv = DINV ? dinv[gr] : 1.f;
#pragma unroll
      for (int nt = 0; nt < NT; ++nt) {
        int gc = col0 + waveN * WNc + nt * 16 + m16;
        if (NCLIP > 0 && gc >= NCLIP) continue;
        float v = acc[mt][nt][r];
        if (BIAS) v += bias[gc];
        if (DINV) v *= dv;
        if (RELU) v = fmaxf(v, 0.f);
        if (SF32) Cf[(size_t)gr * ldc + gc] = v;
        if (SBF16) Cb[(size_t)gr * ldc + gc] = (bf16)v;
      }
    }
  }
}

// ---------------- fallback (R1 proven path) ----------------
__global__ __launch_bounds__(64) void k_aggregate_old(
    const float* __restrict__ xw, const float* __restrict__ dinv,
    const int* __restrict__ offs, const int* __restrict__ cnt,
    const int* __restrict__ csr, const float* __restrict__ b_gcn,
    bf16* __restrict__ x1, int n) {
  int node = blockIdx.x;
  if (node >= n) return;
  int lane = threadIdx.x;
  float di = dinv[node];
  float2 v = ((const float2*)(xw + (size_t)node * G_CH))[lane];
  float ax = v.x * di, ay = v.y * di;
  int beg = offs[node], c = cnt[node];
  for (int i = 0; i < c; ++i) {
    int s = csr[beg + i];
    float ds = dinv[s];
    float2 u = ((const float2*)(xw + (size_t)s * G_CH))[lane];
    ax += u.x * ds; ay += u.y * ds;
  }
  x1[(size_t)node * G_CH + 2 * lane] = (bf16)fmaxf(ax * di + b_gcn[2 * lane], 0.f);
  x1[(size_t)node * G_CH + 2 * lane + 1] = (bf16)fmaxf(ay * di + b_gcn[2 * lane + 1], 0.f);
}

template<int BM, int BN, int BK, int WAVES_M, int WAVES_N, bool RELU, bool BIAS, int NCLIP>
__global__ __launch_bounds__(256) void k_gemm_old(
    const float* __restrict__ A1, int lda1, int K1,
    const bf16* __restrict__ A2, int lda2,
    const bf16* __restrict__ BT, int K,
    const float* __restrict__ bias,
    float* __restrict__ C, int ldc, int M) {
  constexpr int LDA = BK + 8;
  constexpr int WMr = BM / WAVES_M, WNc = BN / WAVES_N;
  constexpr int MT = WMr / 16, NT = WNc / 16;
  __shared__ __align__(16) bf16 Al[BM][LDA];
  __shared__ __align__(16) bf16 Bl[BN][LDA];
  int tid = threadIdx.x, lane = tid & 63, w = tid >> 6;
  int waveM = w / WAVES_N, waveN = w % WAVES_N;
  int row0 = blockIdx.x * BM, col0 = blockIdx.y * BN;
  int aRow = waveM * WMr + (lane & 15);
  int bRow = waveN * WNc + (lane & 15);
  int kLane = (lane >> 4) * 8;
  floatx4_t acc[MT][NT];
#pragma unroll
  for (int i = 0; i < MT; ++i)
#pragma unroll
    for (int j = 0; j < NT; ++j) acc[i][j] = (floatx4_t){0.f, 0.f, 0.f, 0.f};
  for (int k0 = 0; k0 < K; k0 += BK) {
    if (A2 == nullptr || k0 < K1) {
#pragma unroll
      for (int c = 0; c < (BM * BK / 4) / 256; ++c) {
        int ci = c * 256 + tid;
        int r = ci / (BK / 4), c4 = ci % (BK / 4);
        int gr = row0 + r;
        float4 v = {0.f, 0.f, 0.f, 0.f};
        if (gr < M) v = *(const float4*)(A1 + (size_t)gr * lda1 + k0 + c4 * 4);
        bf16x4_t pkt = {(bf16)v.x, (bf16)v.y, (bf16)v.z, (bf16)v.w};
        *(bf16x4_t*)&Al[r][c4 * 4] = pkt;
      }
    } else {
#pragma unroll
      for (int c = 0; c < (BM * BK / 8) / 256; ++c) {
        int ci = c * 256 + tid;
        int r = ci / (BK / 8), c8 = ci % (BK / 8);
        int gr = row0 + r;
        bf16x8_t v = {(bf16)0.f,(bf16)0.f,(bf16)0.f,(bf16)0.f,
                      (bf16)0.f,(bf16)0.f,(bf16)0.f,(bf16)0.f};
        if (gr < M) v = *(const bf16x8_t*)(A2 + (size_t)gr * lda2 + (k0 - K1) + c8 * 8);
        *(bf16x8_t*)&Al[r][c8 * 8] = v;
      }
    }
    for (int ci = tid; ci < BN * (BK / 8); ci += 256) {
      int nrow = ci / (BK / 8), c8 = ci % (BK / 8);
      bf16x8_t v = *(const bf16x8_t*)(BT + (size_t)(col0 + nrow) * K + k0 + c8 * 8);
      *(bf16x8_t*)&Bl[nrow][c8 * 8] = v;
    }
    __syncthreads();
#pragma unroll
    for (int kk = 0; kk < BK; kk += 32) {
      bf16x8_t af[MT], bfr[NT];
#pragma unroll
      for (int mt = 0; mt < MT; ++mt)
        af[mt] = *(const bf16x8_t*)&Al[aRow + mt * 16][kk + kLane];
#pragma unroll
      for (int nt = 0; nt < NT; ++nt)
        bfr[nt] = *(const bf16x8_t*)&Bl[bRow + nt * 16][kk + kLane];
#pragma unroll
      for (int mt = 0; mt < MT; ++mt)
#pragma unroll
        for (int nt = 0; nt < NT; ++nt)
          acc[mt][nt] = __builtin_amdgcn_mfma_f32_16x16x32_bf16(
              af[mt], bfr[nt], acc[mt][nt], 0, 0, 0);
    }
    __syncthreads();
  }
#pragma unroll
  for (int mt = 0; mt < MT; ++mt) {
    int gr0 = row0 + waveM * WMr + mt * 16 + (lane >> 4) * 4;
#pragma unroll
    for (int r = 0; r < 4; ++r) {
      int gr = gr0 + r;
      if (gr >= M) continue;
#pragma unroll
      for (int nt = 0; nt < NT; ++nt) {
        int gc = col0 + waveN * WNc + nt * 16 + (lane & 15);
        if (NCLIP > 0 && gc >= NCLIP) continue;
        float v = acc[mt][nt][r];
        if (BIAS) v += bias[gc];
        if (RELU) v = fmaxf(v, 0.f);
        C[(size_t)gr * ldc + gc] = v;
      }
    }
  }
}

// ---------------- launcher ----------------
extern "C" void kernel_launch(void* const* d_in, const int* in_sizes, int n_in,
                              void* d_out, int out_size, void* d_ws, size_t ws_size,
                              hipStream_t stream) {
  (void)n_in; (void)out_size;
  const float* x  = (const float*)d_in[0];
  const int*   ei = (const int*)d_in[1];
  const float* Wg = (const float*)d_in[3];
  const float* bg = (const float*)d_in[4];
  const float* Wh = (const float*)d_in[5];
  const float* bh = (const float*)d_in[6];
  const float* Wc = (const float*)d_in[7];
  const float* bc = (const float*)d_in[8];
  float* out = (float*)d_out;

  int Nn = in_sizes[0] / IN_CH;   // 100000
  int E  = in_sizes[1] / 2;       // 625000
  const int* e_src = ei;
  const int* e_dst = ei + E;

  int Npad = Nn + 128;
  int gN = (Nn + 255) / 256;
  int gE = (E + 255) / 256;
  int gM = (Nn + 127) / 128;

  char* p = (char*)d_ws;
  auto carve = [&](size_t bytes) -> char* {
    char* q = p; p += (bytes + 255) & ~(size_t)255; return q;
  };

  // fast-path footprint
  size_t need = 0;
  {
    auto acc = [&](size_t b) { need += (b + 255) & ~(size_t)255; };
    acc((size_t)G_CH * IN_CH * 2); acc((size_t)HID * KCAT * 2); acc((size_t)80 * HID * 2);
    acc((size_t)Npad * KCAT * 2); acc((size_t)Npad * G_CH * 2); acc((size_t)Npad * HID * 2);
    acc((size_t)Nn * 4); acc((size_t)Nn * 4); acc((size_t)Nn * 4); acc((size_t)Nn * 4);
    acc((size_t)E * 4);
  }

  if (ws_size >= need) {
    // ---------- fast path: all-bf16 async GEMMs ----------
    bf16*  wgT    = (bf16*)carve((size_t)G_CH * IN_CH * 2);
    bf16*  whT    = (bf16*)carve((size_t)HID * KCAT * 2);
    bf16*  wcT    = (bf16*)carve((size_t)80 * HID * 2);
    bf16*  xcat   = (bf16*)carve((size_t)Npad * KCAT * 2);   // [x_bf16 | x1]
    bf16*  xws    = (bf16*)carve((size_t)Npad * G_CH * 2);   // xw * dinv[row]
    bf16*  hbf    = (bf16*)carve((size_t)Npad * HID * 2);    // h in bf16
    int*   cnt    = (int*)carve((size_t)Nn * 4);
    int*   cursor = (int*)carve((size_t)Nn * 4);
    int*   offs   = (int*)carve((size_t)Nn * 4);
    float* dinv   = (float*)carve((size_t)Nn * 4);
    int*   csr    = (int*)carve((size_t)E * 4);

    k_transpose_w<<<(G_CH * IN_CH + 255) / 256, 256, 0, stream>>>(Wg, wgT, IN_CH, G_CH, G_CH);
    k_transpose_w<<<(HID * KCAT + 255) / 256, 256, 0, stream>>>(Wh, whT, KCAT, HID, HID);
    k_transpose_w<<<(80 * HID + 255) / 256, 256, 0, stream>>>(Wc, wcT, HID, NCLS, 80);

    k_zero2<<<gN, 256, 0, stream>>>(cnt, cursor, Nn);
    k_count<<<gE, 256, 0, stream>>>(e_dst, cnt, E);
    k_dinv<<<gN, 256, 0, stream>>>(cnt, dinv, Nn);
    k_scan<<<1, 1024, 0, stream>>>(cnt, offs, Nn);
    k_scatter<<<gE, 256, 0, stream>>>(e_src, e_dst, offs, cursor, csr, E);

    k_convert<<<(Nn * 160 + 255) / 256, 256, 0, stream>>>(x, xcat, Nn * 160);

    // GEMM1: xws = (xcat[:, :1280] @ W_gcn) * dinv[row]  (bf16 out)
    k_gemm_async<128, 128, 2, 2, false, false, true, false, true, 0>
        <<<dim3(1, gM), 256, 0, stream>>>(
        xcat, KCAT, wgT, IN_CH, IN_CH, nullptr, dinv, nullptr, xws, G_CH, Nn);

    // aggregation -> xcat[:, 1280:1408]
    k_aggregate2<<<(Nn + 3) / 4, 256, 0, stream>>>(xws, dinv, offs, cnt, csr, bg, xcat, Nn);

    // GEMM2: h = relu(xcat @ W_hid + b) -> d_out fp32 + hbf bf16
    k_gemm_async<128, 128, 2, 2, true, true, false, true, true, 0>
        <<<dim3(4, gM), 256, 0, stream>>>(
        xcat, KCAT, whT, KCAT, KCAT, bh, nullptr, out, hbf, HID, Nn);

    // GEMM3: logits = hbf @ W_cls + b -> d_out[N*512:]
    k_gemm_async<128, 80, 4, 1, false, true, false, true, false, NCLS>
        <<<dim3(1, gM), 256, 0, stream>>>(
        hbf, HID, wcT, HID, HID, bc, nullptr, out + (size_t)Nn * HID, nullptr, NCLS, Nn);
  } else {
    // ---------- fallback: R1 proven path ----------
    bf16*  wgT    = (bf16*)carve((size_t)G_CH * IN_CH * 2);
    bf16*  whT    = (bf16*)carve((size_t)HID * KCAT * 2);
    bf16*  wcT    = (bf16*)carve((size_t)80 * HID * 2);
    float* xw     = (float*)carve((size_t)Nn * G_CH * 4);
    bf16*  x1     = (bf16*)carve((size_t)Nn * G_CH * 2);
    int*   cnt    = (int*)carve((size_t)Nn * 4);
    int*   cursor = (int*)carve((size_t)Nn * 4);
    int*   offs   = (int*)carve((size_t)Nn * 4);
    float* dinv   = (float*)carve((size_t)Nn * 4);
    int*   csr    = (int*)carve((size_t)E * 4);

    k_transpose_w<<<(G_CH * IN_CH + 255) / 256, 256, 0, stream>>>(Wg, wgT, IN_CH, G_CH, G_CH);
    k_transpose_w<<<(HID * KCAT + 255) / 256, 256, 0, stream>>>(Wh, whT, KCAT, HID, HID);
    k_transpose_w<<<(80 * HID + 255) / 256, 256, 0, stream>>>(Wc, wcT, HID, NCLS, 80);
    k_zero2<<<gN, 256, 0, stream>>>(cnt, cursor, Nn);
    k_count<<<gE, 256, 0, stream>>>(e_dst, cnt, E);
    k_dinv<<<gN, 256, 0, stream>>>(cnt, dinv, Nn);
    k_scan<<<1, 1024, 0, stream>>>(cnt, offs, Nn);
    k_scatter<<<gE, 256, 0, stream>>>(e_src, e_dst, offs, cursor, csr, E);
    k_gemm_old<128, 128, 64, 2, 2, false, false, 0><<<dim3(gM, 1), 256, 0, stream>>>(
        x, IN_CH, IN_CH, nullptr, 0, wgT, IN_CH, nullptr, xw, G_CH, Nn);
    k_aggregate_old<<<Nn, 64, 0, stream>>>(xw, dinv, offs, cnt, csr, bg, x1, Nn);
    k_gemm_old<128, 128, 64, 2, 2, true, true, 0><<<dim3(gM, 4), 256, 0, stream>>>(
        x, IN_CH, IN_CH, x1, G_CH, whT, KCAT, bh, out, HID, Nn);
    k_gemm_old<128, 80, 64, 4, 1, false, true, NCLS><<<dim3(gM, 1), 256, 0, stream>>>(
        out, HID, HID, nullptr, 0, wcT, HID, bc, out + (size_t)Nn * HID, NCLS, Nn);
  }
}